// Round 1
// baseline (299.320 us; speedup 1.0000x reference)
//
#include <hip/hip_runtime.h>
#include <hip/hip_bf16.h>
#include <stdint.h>

// ---------------------------------------------------------------------------
// DifferentialBiomedCLIP: x(128,197,768) f32 -> QKV proj -> 12-head attn with
// differential combine -> output proj. All matmuls in bf16 MFMA (16x16x32),
// f32 accumulation. Threshold is 8 bf16-ulps, sized for this path.
// ---------------------------------------------------------------------------

typedef __attribute__((ext_vector_type(4))) float f32x4;
typedef __attribute__((ext_vector_type(8))) short s16x8;
typedef __attribute__((ext_vector_type(8))) __bf16 bf16x8;

typedef const __attribute__((address_space(1))) void* gptr_t;
typedef __attribute__((address_space(3))) void* lptr_t;

__device__ __forceinline__ f32x4 mfma16(s16x8 a, s16x8 b, f32x4 c) {
  return __builtin_amdgcn_mfma_f32_16x16x32_bf16(
      __builtin_bit_cast(bf16x8, a), __builtin_bit_cast(bf16x8, b), c, 0, 0, 0);
}

__device__ __forceinline__ short f2bf(float f) {  // RNE f32->bf16 bits
  unsigned u = __float_as_uint(f);
  u += 0x7fffu + ((u >> 16) & 1u);
  return (short)(u >> 16);
}
__device__ __forceinline__ float bf2f(short s) {
  return __uint_as_float(((unsigned)(unsigned short)s) << 16);
}

__device__ __forceinline__ void gload_lds16(const void* g, void* l) {
  // async global->LDS, 16B per lane; LDS dest = wave-uniform base + lane*16
  __builtin_amdgcn_global_load_lds((gptr_t)g, (lptr_t)l, 16, 0, 0);
}

// ---------------------------------------------------------------------------
__global__ void cvt_f32_to_bf16(const float* __restrict__ src,
                                short* __restrict__ dst, long n8) {
  long i = (long)blockIdx.x * blockDim.x + threadIdx.x;
  const long stride = (long)gridDim.x * blockDim.x;
  for (; i < n8; i += stride) {
    const float4 a = ((const float4*)src)[2 * i];
    const float4 b = ((const float4*)src)[2 * i + 1];
    s16x8 o;
    o[0] = f2bf(a.x); o[1] = f2bf(a.y); o[2] = f2bf(a.z); o[3] = f2bf(a.w);
    o[4] = f2bf(b.x); o[5] = f2bf(b.y); o[6] = f2bf(b.z); o[7] = f2bf(b.w);
    ((s16x8*)dst)[i] = o;
  }
}

// lv = mean_h(exp(min(lq1.lk1,5)) - exp(min(lq2.lk2,5))) + lambda_init
__global__ void lv_kernel(const float* __restrict__ lq1, const float* __restrict__ lk1,
                          const float* __restrict__ lq2, const float* __restrict__ lk2,
                          const float* __restrict__ lambda_init, float* __restrict__ out) {
  const int l = threadIdx.x;
  float v = 0.f;
  if (l < 6) {
    float d1 = 0.f, d2 = 0.f;
    for (int j = 0; j < 64; ++j) {
      d1 += lq1[l * 64 + j] * lk1[l * 64 + j];
      d2 += lq2[l * 64 + j] * lk2[l * 64 + j];
    }
    v = expf(fminf(d1, 5.f)) - expf(fminf(d2, 5.f));
  }
  v += __shfl_xor(v, 1, 64);
  v += __shfl_xor(v, 2, 64);
  v += __shfl_xor(v, 4, 64);
  if (l == 0) out[0] = v * (1.f / 6.f) + lambda_init[0];
}

// ---------------------------------------------------------------------------
// C[M,N] = A[M,K] * B[N,K]^T + bias ; A row stride = lda (elements), B packed.
// 128x128 tile, BK=64, 4 waves, 16x16x32 bf16 MFMA, global_load_lds staging,
// XOR chunk swizzle (pre-swizzled global source + swizzled LDS read, rule #21).
template <int OUT_BF16>
__global__ __launch_bounds__(256) void gemm_bt(const short* __restrict__ A, int lda,
                                               const short* __restrict__ B,
                                               const float* __restrict__ bias,
                                               void* __restrict__ C,
                                               int M, int N, int K) {
  const int nbx = N >> 7;
  const int bx = blockIdx.x % nbx;
  const int by = blockIdx.x / nbx;
  const long m0 = (long)by << 7;
  const int n0 = bx << 7;
  __shared__ short Asm[128 * 64];
  __shared__ short Bsm[128 * 64];
  const int tid = threadIdx.x;
  const int lane = tid & 63;
  const int w = tid >> 6;
  const int wr = w >> 1, wc = w & 1;
  const int r16 = lane & 15, g = lane >> 4;
  f32x4 acc[4][4];
#pragma unroll
  for (int i = 0; i < 4; ++i)
#pragma unroll
    for (int j = 0; j < 4; ++j) acc[i][j] = f32x4{0.f, 0.f, 0.f, 0.f};

  const int nkt = K >> 6;
  for (int kt = 0; kt < nkt; ++kt) {
    __syncthreads();  // all waves done reading LDS from previous step
#pragma unroll
    for (int i = 0; i < 4; ++i) {
      const int c = i * 256 + tid;      // linear 16B chunk id (1024 per tile)
      const int row = c >> 3;           // 8 chunks per 64-elem row
      const int lc = (c & 7) ^ (row & 7);  // logical col-chunk for this slot
      gload_lds16(A + (m0 + row) * lda + (long)kt * 64 + lc * 8,
                  Asm + i * 2048 + w * 512);
      gload_lds16(B + (long)(n0 + row) * K + (long)kt * 64 + lc * 8,
                  Bsm + i * 2048 + w * 512);
    }
    asm volatile("s_waitcnt vmcnt(0)" ::: "memory");
    __syncthreads();
#pragma unroll
    for (int kk = 0; kk < 2; ++kk) {
      s16x8 av[4], bvv[4];
#pragma unroll
      for (int f = 0; f < 4; ++f) {
        const int ar = wr * 64 + f * 16 + r16;
        av[f] = *(const s16x8*)(Asm + ar * 64 + ((((kk << 2) + g) ^ (ar & 7)) << 3));
        const int br = wc * 64 + f * 16 + r16;
        bvv[f] = *(const s16x8*)(Bsm + br * 64 + ((((kk << 2) + g) ^ (br & 7)) << 3));
      }
#pragma unroll
      for (int fm = 0; fm < 4; ++fm)
#pragma unroll
        for (int fn = 0; fn < 4; ++fn)
          acc[fm][fn] = mfma16(av[fm], bvv[fn], acc[fm][fn]);
    }
  }
  // epilogue: D col=lane&15, row=(lane>>4)*4+reg
#pragma unroll
  for (int fm = 0; fm < 4; ++fm)
#pragma unroll
    for (int fn = 0; fn < 4; ++fn) {
      const int col = n0 + wc * 64 + fn * 16 + r16;
      const float bb = bias[col];
#pragma unroll
      for (int r = 0; r < 4; ++r) {
        const long row = m0 + wr * 64 + fm * 16 + g * 4 + r;
        const float v = acc[fm][fn][r] + bb;
        if (OUT_BF16) ((short*)C)[row * (long)N + col] = f2bf(v);
        else          ((float*)C)[row * (long)N + col] = v;
      }
    }
}

// ---------------------------------------------------------------------------
// Attention: one block per (b,h). QKV (25216 x 2304) bf16: cols [0,768)=Q,
// [768,1536)=K, [1536,2304)=V, head-major (h*64+d). Writes O in place over the
// Q columns (each wave reads its own Q rows before writing them).
__global__ __launch_bounds__(256) void attn_kernel(short* QKV) {
  const int b = blockIdx.x / 12;
  const int h = blockIdx.x % 12;
  __shared__ short Ksm[208 * 72];   // keys padded to 208, row stride 72 elems
  __shared__ short Vsm[64 * 232];   // V transposed [d][key], stride 232 elems
  __shared__ short Psm[4][512];     // per-wave 16x32 bf16 P bounce (swizzled)
  const int tid = threadIdx.x;
  const long base = (long)b * 197 * 2304;

  for (int c = tid; c < 208 * 8; c += 256) {  // stage K
    const int key = c >> 3, dch = c & 7;
    s16x8 val = {};
    if (key < 197)
      val = *(const s16x8*)(QKV + base + (long)key * 2304 + 768 + h * 64 + dch * 8);
    *(s16x8*)(Ksm + key * 72 + dch * 8) = val;
  }
  for (int c = tid; c < 224 * 8; c += 256) {  // stage V transposed (224 keys for PV pad)
    const int key = c % 224, dch = c / 224;
    s16x8 val = {};
    if (key < 197)
      val = *(const s16x8*)(QKV + base + (long)key * 2304 + 1536 + h * 64 + dch * 8);
#pragma unroll
    for (int j = 0; j < 8; ++j) Vsm[(dch * 8 + j) * 232 + key] = val[j];
  }
  __syncthreads();

  const int lane = tid & 63, w = tid >> 6;
  const int r16 = lane & 15, g = lane >> 4;
  short* psw = Psm[w];

  for (int qt = w; qt < 13; qt += 4) {  // 13 q-tiles of 16 rows, round-robin
    const int q0 = qt * 16;
    int qr = q0 + r16;
    if (qr > 196) qr = 196;  // clamp; clamped rows computed but never stored
    const s16x8 qf0 = *(const s16x8*)(QKV + base + (long)qr * 2304 + h * 64 + g * 8);
    const s16x8 qf1 = *(const s16x8*)(QKV + base + (long)qr * 2304 + h * 64 + 32 + g * 8);

    f32x4 s[13];
#pragma unroll
    for (int kt = 0; kt < 13; ++kt) s[kt] = f32x4{0.f, 0.f, 0.f, 0.f};
#pragma unroll
    for (int kt = 0; kt < 13; ++kt) {
      const int krow = kt * 16 + r16;
      const s16x8 kf0 = *(const s16x8*)(Ksm + krow * 72 + g * 8);
      const s16x8 kf1 = *(const s16x8*)(Ksm + krow * 72 + 32 + g * 8);
      s[kt] = mfma16(qf0, kf0, s[kt]);
      s[kt] = mfma16(qf1, kf1, s[kt]);
    }
    // scale, mask pad keys, row max (rows live at (lane>>4)*4+reg, key=lane&15)
    float mr[4] = {-1e30f, -1e30f, -1e30f, -1e30f};
#pragma unroll
    for (int kt = 0; kt < 13; ++kt)
#pragma unroll
      for (int r = 0; r < 4; ++r) {
        float sv = s[kt][r] * 0.125f;
        if (kt == 12 && r16 >= 5) sv = -1e30f;  // keys 197..207
        s[kt][r] = sv;
        mr[r] = fmaxf(mr[r], sv);
      }
#pragma unroll
    for (int r = 0; r < 4; ++r) {
      mr[r] = fmaxf(mr[r], __shfl_xor(mr[r], 1, 64));
      mr[r] = fmaxf(mr[r], __shfl_xor(mr[r], 2, 64));
      mr[r] = fmaxf(mr[r], __shfl_xor(mr[r], 4, 64));
      mr[r] = fmaxf(mr[r], __shfl_xor(mr[r], 8, 64));
    }
    float sum[4] = {0.f, 0.f, 0.f, 0.f};
#pragma unroll
    for (int kt = 0; kt < 13; ++kt)
#pragma unroll
      for (int r = 0; r < 4; ++r) {
        const float p = __expf(s[kt][r] - mr[r]);
        s[kt][r] = p;
        sum[r] += p;
      }
#pragma unroll
    for (int r = 0; r < 4; ++r) {
      sum[r] += __shfl_xor(sum[r], 1, 64);
      sum[r] += __shfl_xor(sum[r], 2, 64);
      sum[r] += __shfl_xor(sum[r], 4, 64);
      sum[r] += __shfl_xor(sum[r], 8, 64);
    }
    // PV: bounce P through per-wave swizzled LDS tile into MFMA-A layout
    f32x4 o[4];
#pragma unroll
    for (int df = 0; df < 4; ++df) o[df] = f32x4{0.f, 0.f, 0.f, 0.f};
#pragma unroll
    for (int kb = 0; kb < 7; ++kb) {  // 7 blocks of 32 keys (last half-padded)
#pragma unroll
      for (int r = 0; r < 4; ++r) {
        const int prow = g * 4 + r;
        const int sw = (prow & 7) << 4;
        const float p1f = (kb < 6) ? s[(2 * kb + 1) % 13][r] : 0.f;
        *(short*)((char*)psw + ((prow * 64 + r16 * 2) ^ sw)) = f2bf(s[2 * kb][r]);
        *(short*)((char*)psw + ((prow * 64 + (r16 + 16) * 2) ^ sw)) = f2bf(p1f);
      }
      asm volatile("s_waitcnt lgkmcnt(0)" ::: "memory");
      const s16x8 pa =
          *(const s16x8*)((const char*)psw + ((r16 * 64 + g * 16) ^ ((r16 & 7) << 4)));
#pragma unroll
      for (int df = 0; df < 4; ++df) {
        const s16x8 vf = *(const s16x8*)(Vsm + (df * 16 + r16) * 232 + kb * 32 + g * 8);
        o[df] = mfma16(pa, vf, o[df]);
      }
    }
    float rinv[4];
#pragma unroll
    for (int r = 0; r < 4; ++r) rinv[r] = 1.f / sum[r];
#pragma unroll
    for (int df = 0; df < 4; ++df)
#pragma unroll
      for (int r = 0; r < 4; ++r) {
        const int qrow = q0 + g * 4 + r;
        if (qrow < 197)
          QKV[base + (long)qrow * 2304 + h * 64 + df * 16 + r16] =
              f2bf(o[df][r] * rinv[r]);
      }
  }
}

// ocat[:, 0:384] = o1 - lv*o2 (in place over Q-columns of QKV)
__global__ void combine_kernel(short* __restrict__ QKV, const float* __restrict__ lvp) {
  const float lv = *lvp;
  const long total = (long)25216 * 48;  // 384 cols / 8 per chunk
  const long stride = (long)gridDim.x * blockDim.x;
  for (long i = (long)blockIdx.x * blockDim.x + threadIdx.x; i < total; i += stride) {
    const long m = i / 48;
    const int jv = (int)(i - m * 48);
    short* p1 = QKV + m * 2304 + jv * 8;
    const s16x8 a = *(const s16x8*)p1;
    const s16x8 c2 = *(const s16x8*)(p1 + 384);
    s16x8 r;
#pragma unroll
    for (int j = 0; j < 8; ++j) r[j] = f2bf(bf2f(a[j]) - lv * bf2f(c2[j]));
    *(s16x8*)p1 = r;
  }
}

// ---------------------------------------------------------------------------
extern "C" void kernel_launch(void* const* d_in, const int* in_sizes, int n_in,
                              void* d_out, int out_size, void* d_ws, size_t ws_size,
                              hipStream_t stream) {
  (void)in_sizes; (void)n_in; (void)out_size; (void)ws_size;
  const float* x   = (const float*)d_in[0];
  const float* Wq  = (const float*)d_in[1];
  const float* bq  = (const float*)d_in[2];
  const float* Wk  = (const float*)d_in[3];
  const float* bk  = (const float*)d_in[4];
  const float* Wv  = (const float*)d_in[5];
  const float* bv  = (const float*)d_in[6];
  const float* Wp  = (const float*)d_in[7];
  const float* bp  = (const float*)d_in[8];
  const float* lq1 = (const float*)d_in[9];
  const float* lk1 = (const float*)d_in[10];
  const float* lq2 = (const float*)d_in[11];
  const float* lk2 = (const float*)d_in[12];
  const float* lambda_init = (const float*)d_in[14];

  // workspace layout (bytes, 256-aligned); total 159,655,168
  char* ws = (char*)d_ws;
  short* xb   = (short*)ws;                  // x bf16: 25216x768
  short* wqkv = (short*)(ws + 38731776);     // [Wq;Wk;Wv] bf16: 2304x768
  short* wpb  = (short*)(ws + 42270720);     // Wp bf16: 768x768
  float* bqkv = (float*)(ws + 43450368);     // [bq;bk;bv] f32: 2304
  float* lvp  = (float*)(ws + 43459584);     // lv scalar
  short* qkv  = (short*)(ws + 43459840);     // QKV bf16: 25216x2304 (O aliases Q cols)

  cvt_f32_to_bf16<<<2048, 256, 0, stream>>>(x, xb, 19365888 / 8);
  cvt_f32_to_bf16<<<288, 256, 0, stream>>>(Wq, wqkv, 73728);
  cvt_f32_to_bf16<<<288, 256, 0, stream>>>(Wk, wqkv + 589824, 73728);
  cvt_f32_to_bf16<<<288, 256, 0, stream>>>(Wv, wqkv + 1179648, 73728);
  cvt_f32_to_bf16<<<288, 256, 0, stream>>>(Wp, wpb, 73728);
  hipMemcpyAsync(bqkv,        bq, 768 * 4, hipMemcpyDeviceToDevice, stream);
  hipMemcpyAsync(bqkv + 768,  bk, 768 * 4, hipMemcpyDeviceToDevice, stream);
  hipMemcpyAsync(bqkv + 1536, bv, 768 * 4, hipMemcpyDeviceToDevice, stream);
  lv_kernel<<<1, 64, 0, stream>>>(lq1, lk1, lq2, lk2, lambda_init, lvp);

  gemm_bt<1><<<197 * 18, 256, 0, stream>>>(xb, 768, wqkv, bqkv, qkv, 25216, 2304, 768);
  attn_kernel<<<128 * 12, 256, 0, stream>>>(qkv);
  combine_kernel<<<1024, 256, 0, stream>>>(qkv, lvp);
  gemm_bt<0><<<197 * 6, 256, 0, stream>>>(qkv, 2304, wpb, bp, d_out, 25216, 768, 768);
}